// Round 2
// baseline (4015.851 us; speedup 1.0000x reference)
//
#include <hip/hip_runtime.h>
#include <stdint.h>
#include <stddef.h>

// ---------------------------------------------------------------------------
// Problem: TwoHemiRNNTanh_asymmetric_single_readout
// B=512, T=400, N=256 (hidden 258 = 2 left + 256 right)
// Outputs: hs (512,400,258) f32, zs (512,400,1) f32, concatenated in d_out.
//
// RNG assumption (ROUND 1): jax_threefry_partitionable = True (JAX >= 0.4.36
// default). split(key,3) fold-like: nk[i] = threefry2x32((0,42),(0,i)) pair.
// random_bits(key,32,shape)[i] = o0 ^ o1 of threefry2x32(key,(0,i)), i = flat
// row-major index. normal = sqrt(2)*erfinv(uniform(-0.99999994, 1.0)).
// If this round fails with absmax ~0.3-1.0 -> flip to legacy halved-iota path.
// ---------------------------------------------------------------------------

#define TF_ROUND(x0, x1, r) { x0 += x1; x1 = ((x1) << (r)) | ((x1) >> (32 - (r))); x1 ^= x0; }

__host__ __device__ inline void tf2x32(uint32_t k0, uint32_t k1, uint32_t x0, uint32_t x1,
                                       uint32_t& o0, uint32_t& o1) {
  uint32_t ks2 = k0 ^ k1 ^ 0x1BD11BDAu;
  x0 += k0; x1 += k1;
  TF_ROUND(x0, x1, 13) TF_ROUND(x0, x1, 15) TF_ROUND(x0, x1, 26) TF_ROUND(x0, x1, 6)
  x0 += k1; x1 += ks2 + 1u;
  TF_ROUND(x0, x1, 17) TF_ROUND(x0, x1, 29) TF_ROUND(x0, x1, 16) TF_ROUND(x0, x1, 24)
  x0 += ks2; x1 += k0 + 2u;
  TF_ROUND(x0, x1, 13) TF_ROUND(x0, x1, 15) TF_ROUND(x0, x1, 26) TF_ROUND(x0, x1, 6)
  x0 += k0; x1 += k1 + 3u;
  TF_ROUND(x0, x1, 17) TF_ROUND(x0, x1, 29) TF_ROUND(x0, x1, 16) TF_ROUND(x0, x1, 24)
  x0 += k1; x1 += ks2 + 4u;
  TF_ROUND(x0, x1, 13) TF_ROUND(x0, x1, 15) TF_ROUND(x0, x1, 26) TF_ROUND(x0, x1, 6)
  x0 += ks2; x1 += k0 + 5u;
  o0 = x0; o1 = x1;
}

// XLA f32 ErfInv (Giles polynomial) — matches CPU/GPU XLA lowering closely.
__device__ __forceinline__ float jax_erfinv(float x) {
  float w = -log1pf(-x * x);
  float p;
  if (w < 5.0f) {
    w -= 2.5f;
    p = 2.81022636e-08f;
    p = fmaf(p, w, 3.43273939e-07f);
    p = fmaf(p, w, -3.5233877e-06f);
    p = fmaf(p, w, -4.39150654e-06f);
    p = fmaf(p, w, 0.00021858087f);
    p = fmaf(p, w, -0.00125372503f);
    p = fmaf(p, w, -0.00417768164f);
    p = fmaf(p, w, 0.246640727f);
    p = fmaf(p, w, 1.50140941f);
  } else {
    w = sqrtf(w) - 3.0f;
    p = -0.000200214257f;
    p = fmaf(p, w, 0.000100950558f);
    p = fmaf(p, w, 0.00134934322f);
    p = fmaf(p, w, -0.00367342844f);
    p = fmaf(p, w, 0.00573950773f);
    p = fmaf(p, w, -0.0076224613f);
    p = fmaf(p, w, 0.00943887047f);
    p = fmaf(p, w, 1.00167406f);
    p = fmaf(p, w, 2.83297682f);
  }
  return p * x;
}

__device__ __forceinline__ float uni_from_bits(uint32_t bits) {
  // JAX _uniform: u = bitcast((bits>>9)|0x3f800000) - 1 in [0,1);
  // x = u*(hi-lo)+lo with lo=-0.99999994f, (hi-lo) folds to 2.0f; clamp at lo.
  float f = __uint_as_float((bits >> 9) | 0x3f800000u) - 1.0f;
  float x = f * 2.0f + (-0.99999994f);
  return fmaxf(-0.99999994f, x);
}

__device__ __forceinline__ float noise_from_bits(uint32_t bits) {
  // sqrt(2)*erfinv(u) then * (scale*SIG) ; scale*SIG = sqrt(10)*0.05
  float n = 1.41421356f * jax_erfinv(uni_from_bits(bits));
  return 0.15811388f * n;
}

__device__ __forceinline__ float my_tanh(float x) {
  float e = __expf(2.0f * x);
  return 1.0f - 2.0f / (e + 1.0f);
}

// ---------------------------------------------------------------------------
// K_w: build fused recurrent matrix. W[j][k], j=output(258), k=input(258).
//   j<2 : k<2 -> w_ll[j][k]      else w_rl[j][k-2]
//   j>=2: k<2 -> w_lr[j-2][k]    else w_rr[j-2][k-2]
// Wmain [258][256] (k<256), Wtail [258][2] (k=256,257).
// ---------------------------------------------------------------------------
__global__ __launch_bounds__(256) void build_w_kernel(
    const float* __restrict__ w_ll, const float* __restrict__ w_rl,
    const float* __restrict__ w_lr, const float* __restrict__ w_rr,
    float* __restrict__ Wmain, float* __restrict__ Wtail) {
  int i = blockIdx.x * 256 + threadIdx.x;
  if (i >= 258 * 258) return;
  int j = i / 258, k = i - j * 258;
  float val;
  if (j < 2) val = (k < 2) ? w_ll[j * 2 + k] : w_rl[j * 256 + (k - 2)];
  else       val = (k < 2) ? w_lr[(j - 2) * 2 + k] : w_rr[(j - 2) * 256 + (k - 2)];
  if (k < 256) Wmain[j * 256 + k] = val;
  else         Wtail[j * 2 + (k - 256)] = val;
}

// ---------------------------------------------------------------------------
// K_uv: u = xs + noise_l (key nk0), v = xs + noise_r (key nk1). (B,T,2) each.
// ---------------------------------------------------------------------------
__global__ __launch_bounds__(256) void gen_uv_kernel(
    const float* __restrict__ xs, float* __restrict__ u, float* __restrict__ v,
    uint32_t k0a, uint32_t k0b, uint32_t k1a, uint32_t k1b) {
  uint32_t i = blockIdx.x * 256u + threadIdx.x;   // 0 .. 819199
  bool isv = i >= 409600u;
  uint32_t e = isv ? i - 409600u : i;
  uint32_t ka = isv ? k1a : k0a;
  uint32_t kb = isv ? k1b : k0b;
  uint32_t o0, o1;
  tf2x32(ka, kb, 0u, e, o0, o1);
  float val = xs[e] + noise_from_bits(o0 ^ o1);
  if (isv) v[e] = val; else u[e] = val;
}

// ---------------------------------------------------------------------------
// K_c: C[b][t][j] = x_inj[b,t,j] + rec_noise[t,b,j] + bias[j], written into
// the hs region of d_out (consumed in-place by the scan before overwrite).
// rec_noise flat index (PRNG) is over shape (T,B,258).
// ---------------------------------------------------------------------------
__global__ __launch_bounds__(256) void gen_c_kernel(
    const float* __restrict__ u, const float* __restrict__ v,
    const float* __restrict__ w_xl, const float* __restrict__ w_xr,
    const float* __restrict__ b_ll, const float* __restrict__ b_rr,
    float* __restrict__ C, uint32_t ka, uint32_t kb) {
  uint32_t i = blockIdx.x * 256u + threadIdx.x;   // < 52,838,400 exact
  uint32_t t = i / 132096u;                        // 132096 = 512*258
  uint32_t rem = i - t * 132096u;
  uint32_t b = rem / 258u;
  uint32_t j = rem - b * 258u;
  uint32_t o0, o1;
  tf2x32(ka, kb, 0u, i, o0, o1);
  float nz = noise_from_bits(o0 ^ o1);
  uint32_t bt = (b * 400u + t) * 2u;
  float inj;
  if (j < 2u) {
    float2 uu = *(const float2*)(u + bt);
    inj = w_xl[j * 2u] * uu.x + w_xl[j * 2u + 1u] * uu.y + b_ll[j];
  } else {
    uint32_t jr = j - 2u;
    float2 vv = *(const float2*)(v + bt);
    inj = w_xr[jr * 2u] * vv.x + w_xr[jr * 2u + 1u] * vv.y + b_rr[jr];
  }
  C[(size_t)(b * 400u + t) * 258u + j] = inj + nz;
}

// ---------------------------------------------------------------------------
// K_scan: 256 blocks x 1024 threads; block handles batch rows b0=2*blk, b0+1.
// Thread (g=tid>>3, ks=tid&7): W rows joutA=g+2, joutB=g+130, k-chunk
// [32ks,32ks+32) in registers (64 f32). h kept in LDS double-buffer with
// skewed chunk stride 36 dwords (bank-conflict-free b128 reads). 8-lane
// shuffle reduction; lanes ks=0/1 update rows 0/1. Left outputs (j=0,1)
// computed by wave 0 via 64-lane k-split + butterfly, updated by lanes 32/33.
// One __syncthreads per step. C is read from d_out and overwritten with h.
// ---------------------------------------------------------------------------
#define HROW 292

__device__ __forceinline__ void dot4(float& acc, const float* W, int o, float4 q) {
  acc = fmaf(W[o], q.x, acc);
  acc = fmaf(W[o + 1], q.y, acc);
  acc = fmaf(W[o + 2], q.z, acc);
  acc = fmaf(W[o + 3], q.w, acc);
}

__global__ __launch_bounds__(1024) void rnn_scan_kernel(
    const float* __restrict__ Wmain, const float* __restrict__ Wtail,
    float* __restrict__ hsC) {
  __shared__ __align__(16) float hbuf[4 * HROW];
  __shared__ __align__(16) float wlds[512];

  const int tid = threadIdx.x;
  const int b0 = blockIdx.x * 2;
  const int ks = tid & 7;
  const int g = tid >> 3;
  const int joutA = g + 2;
  const int joutB = g + 130;

  // --- persistent W registers ---
  float wA[32], wB[32];
  {
    const float* pA = Wmain + joutA * 256 + ks * 32;
    const float* pB = Wmain + joutB * 256 + ks * 32;
#pragma unroll
    for (int c = 0; c < 8; ++c) {
      float4 a = *(const float4*)(pA + 4 * c);
      float4 bq = *(const float4*)(pB + 4 * c);
      wA[4 * c] = a.x; wA[4 * c + 1] = a.y; wA[4 * c + 2] = a.z; wA[4 * c + 3] = a.w;
      wB[4 * c] = bq.x; wB[4 * c + 1] = bq.y; wB[4 * c + 2] = bq.z; wB[4 * c + 3] = bq.w;
    }
  }
  const float wtA0 = Wtail[joutA * 2], wtA1 = Wtail[joutA * 2 + 1];
  const float wtB0 = Wtail[joutB * 2], wtB1 = Wtail[joutB * 2 + 1];

  const bool lupd = (tid == 32) || (tid == 33);
  float wtL0 = 0.f, wtL1 = 0.f, hL0 = 0.f, hL1 = 0.f;
  if (lupd) { int jo = tid & 1; wtL0 = Wtail[jo * 2]; wtL1 = Wtail[jo * 2 + 1]; }

  float hA = 0.f, hB = 0.f;  // own h values (rows handled by updater lanes)

  if (tid < 512) wlds[tid] = Wmain[tid];  // W rows 0,1 (k<256) for wave 0
  for (int k2 = tid; k2 < 4 * HROW; k2 += 1024) hbuf[k2] = 0.f;
  __syncthreads();

  const int dA = 36 * (joutA >> 5) + (joutA & 31);
  const int dB = 36 * (joutB >> 5) + (joutB & 31);
  const int rr = (ks < 2) ? ks : 0;
  float* outR = hsC + (size_t)(b0 + rr) * 103200;  // row base (updater row)
  float* out0 = hsC + (size_t)b0 * 103200;
  float* out1 = hsC + (size_t)(b0 + 1) * 103200;

#pragma unroll 1
  for (int t = 0; t < 400; ++t) {
    const int cb = t & 1;
    const float* h0 = hbuf + cb * 2 * HROW;
    const float* h1 = h0 + HROW;
    const int tbase = t * 258;

    // prefetch C (per-wave dedup; only updater lanes consume)
    float cA = outR[tbase + joutA];
    float cB = outR[tbase + joutB];
    float cL0 = 0.f, cL1 = 0.f;
    if (lupd) {
      int jo = tid & 1;
      cL0 = out0[tbase + jo];
      cL1 = out1[tbase + jo];
    }

    // --- matvec: partial dots over k = 32ks..32ks+31 for 2 W-rows x 2 batch rows
    float aA0 = 0.f, aA1 = 0.f, aB0 = 0.f, aB1 = 0.f;
    const float* hp0 = h0 + 36 * ks;
    const float* hp1 = h1 + 36 * ks;
#pragma unroll
    for (int c = 0; c < 8; ++c) {
      float4 x0 = *(const float4*)(hp0 + 4 * c);
      float4 x1 = *(const float4*)(hp1 + 4 * c);
      dot4(aA0, wA, 4 * c, x0);
      dot4(aA1, wA, 4 * c, x1);
      dot4(aB0, wB, 4 * c, x0);
      dot4(aB1, wB, 4 * c, x1);
    }

    // --- left outputs (j=0,1), wave 0: k-split over 64 lanes
    float l00 = 0.f, l01 = 0.f, l10 = 0.f, l11 = 0.f;
    if (tid < 64) {
      const int dwo = 36 * (tid >> 3) + ((4 * tid) & 31);
      float4 x0 = *(const float4*)(h0 + dwo);
      float4 x1 = *(const float4*)(h1 + dwo);
      float4 w0v = *(const float4*)(wlds + 4 * tid);
      float4 w1v = *(const float4*)(wlds + 256 + 4 * tid);
      l00 = w0v.x * x0.x + w0v.y * x0.y + w0v.z * x0.z + w0v.w * x0.w;
      l01 = w1v.x * x0.x + w1v.y * x0.y + w1v.z * x0.z + w1v.w * x0.w;
      l10 = w0v.x * x1.x + w0v.y * x1.y + w0v.z * x1.z + w0v.w * x1.w;
      l11 = w1v.x * x1.x + w1v.y * x1.y + w1v.z * x1.z + w1v.w * x1.w;
#pragma unroll
      for (int m = 1; m < 64; m <<= 1) {
        l00 += __shfl_xor(l00, m);
        l01 += __shfl_xor(l01, m);
        l10 += __shfl_xor(l10, m);
        l11 += __shfl_xor(l11, m);
      }
    }

    // --- 8-lane butterfly reduce over ks
#pragma unroll
    for (int m = 1; m < 8; m <<= 1) {
      aA0 += __shfl_xor(aA0, m);
      aA1 += __shfl_xor(aA1, m);
      aB0 += __shfl_xor(aB0, m);
      aB1 += __shfl_xor(aB1, m);
    }

    float* hn = hbuf + (cb ^ 1) * 2 * HROW;

    // --- update: lane ks=r (r=0,1) owns batch-row r for joutA/joutB
    if (ks < 2) {
      const float* hr = ks ? h1 : h0;
      float accA = ks ? aA1 : aA0;
      float accB = ks ? aB1 : aB0;
      float t256 = hr[288], t257 = hr[289];
      float preA = accA + wtA0 * t256 + wtA1 * t257 + cA;
      float preB = accB + wtB0 * t256 + wtB1 * t257 + cB;
      hA = 0.8f * hA + 0.2f * my_tanh(preA);
      hB = 0.8f * hB + 0.2f * my_tanh(preB);
      float* hnr = hn + ks * HROW;
      hnr[dA] = hA;
      hnr[dB] = hB;
      outR[tbase + joutA] = hA;
      outR[tbase + joutB] = hB;
    }
    if (lupd) {
      int jo = tid & 1;
      float a0 = jo ? l01 : l00;
      float a1 = jo ? l11 : l10;
      float pre0 = a0 + wtL0 * h0[288] + wtL1 * h0[289] + cL0;
      float pre1 = a1 + wtL0 * h1[288] + wtL1 * h1[289] + cL1;
      hL0 = 0.8f * hL0 + 0.2f * my_tanh(pre0);
      hL1 = 0.8f * hL1 + 0.2f * my_tanh(pre1);
      hn[jo] = hL0;
      hn[HROW + jo] = hL1;
      out0[tbase + jo] = hL0;
      out1[tbase + jo] = hL1;
    }
    __syncthreads();
  }
}

// ---------------------------------------------------------------------------
// K_z: zs[b,t] = dot(w_ro, hs[b,t,:]) + b_ro. One wave per (b,t) row.
// ---------------------------------------------------------------------------
__global__ __launch_bounds__(256) void zs_kernel(
    const float* __restrict__ hs, const float* __restrict__ w_ro,
    const float* __restrict__ b_ro, float* __restrict__ zs) {
  int gtid = blockIdx.x * 256 + threadIdx.x;
  int row = gtid >> 6;          // 0..204799
  int lane = threadIdx.x & 63;
  const float* hrow = hs + (size_t)row * 258;
  float s = 0.f;
  for (int j = lane; j < 258; j += 64) s = fmaf(hrow[j], w_ro[j], s);
#pragma unroll
  for (int m = 32; m >= 1; m >>= 1) s += __shfl_xor(s, m);
  if (lane == 0) zs[row] = s + b_ro[0];
}

// ---------------------------------------------------------------------------
extern "C" void kernel_launch(void* const* d_in, const int* in_sizes, int n_in,
                              void* d_out, int out_size, void* d_ws, size_t ws_size,
                              hipStream_t stream) {
  const float* xs   = (const float*)d_in[0];
  const float* w_ll = (const float*)d_in[1];
  const float* b_ll = (const float*)d_in[2];
  const float* w_rr = (const float*)d_in[3];
  const float* b_rr = (const float*)d_in[4];
  const float* w_lr = (const float*)d_in[5];
  const float* w_rl = (const float*)d_in[6];
  const float* w_xl = (const float*)d_in[7];
  const float* w_xr = (const float*)d_in[8];
  const float* w_ro = (const float*)d_in[9];
  const float* b_ro = (const float*)d_in[10];

  float* hs = (float*)d_out;                    // 512*400*258 = 52,838,400
  float* zs = hs + (size_t)52838400;            // 204,800

  float* Wmain = (float*)d_ws;                  // 258*256 = 66,048
  float* Wtail = Wmain + 66048;                 // 516
  float* u     = Wtail + 516;                   // 409,600
  float* v     = u + 409600;                    // 409,600

  // host-side: nk = split(key(42), 3), fold-like (partitionable)
  uint32_t nk[3][2];
  for (uint32_t i = 0; i < 3; ++i) {
    uint32_t o0, o1;
    tf2x32(0u, 42u, 0u, i, o0, o1);
    nk[i][0] = o0; nk[i][1] = o1;
  }

  build_w_kernel<<<(258 * 258 + 255) / 256, 256, 0, stream>>>(w_ll, w_rl, w_lr, w_rr, Wmain, Wtail);
  gen_uv_kernel<<<3200, 256, 0, stream>>>(xs, u, v, nk[0][0], nk[0][1], nk[1][0], nk[1][1]);
  gen_c_kernel<<<206400, 256, 0, stream>>>(u, v, w_xl, w_xr, b_ll, b_rr, hs, nk[2][0], nk[2][1]);
  rnn_scan_kernel<<<256, 1024, 0, stream>>>(Wmain, Wtail, hs);
  zs_kernel<<<51200, 256, 0, stream>>>(hs, w_ro, b_ro, zs);
}

// Round 3
// 3431.108 us; speedup vs baseline: 1.1704x; 1.1704x over previous
//
#include <hip/hip_runtime.h>
#include <stdint.h>
#include <stddef.h>

// ---------------------------------------------------------------------------
// TwoHemiRNNTanh_asymmetric_single_readout  (B=512, T=400, hidden 258)
// R2: passed, scan = 3.88ms, 23x HBM amplification from scattered per-lane
//     4B global loads/stores in the step loop.
// R3: coalesced LDS-staged C (1-step register prefetch) + cooperative
//     coalesced hs stores. One barrier/step preserved.
// ---------------------------------------------------------------------------

#define TF_ROUND(x0, x1, r) { x0 += x1; x1 = ((x1) << (r)) | ((x1) >> (32 - (r))); x1 ^= x0; }

__host__ __device__ inline void tf2x32(uint32_t k0, uint32_t k1, uint32_t x0, uint32_t x1,
                                       uint32_t& o0, uint32_t& o1) {
  uint32_t ks2 = k0 ^ k1 ^ 0x1BD11BDAu;
  x0 += k0; x1 += k1;
  TF_ROUND(x0, x1, 13) TF_ROUND(x0, x1, 15) TF_ROUND(x0, x1, 26) TF_ROUND(x0, x1, 6)
  x0 += k1; x1 += ks2 + 1u;
  TF_ROUND(x0, x1, 17) TF_ROUND(x0, x1, 29) TF_ROUND(x0, x1, 16) TF_ROUND(x0, x1, 24)
  x0 += ks2; x1 += k0 + 2u;
  TF_ROUND(x0, x1, 13) TF_ROUND(x0, x1, 15) TF_ROUND(x0, x1, 26) TF_ROUND(x0, x1, 6)
  x0 += k0; x1 += k1 + 3u;
  TF_ROUND(x0, x1, 17) TF_ROUND(x0, x1, 29) TF_ROUND(x0, x1, 16) TF_ROUND(x0, x1, 24)
  x0 += k1; x1 += ks2 + 4u;
  TF_ROUND(x0, x1, 13) TF_ROUND(x0, x1, 15) TF_ROUND(x0, x1, 26) TF_ROUND(x0, x1, 6)
  x0 += ks2; x1 += k0 + 5u;
  o0 = x0; o1 = x1;
}

__device__ __forceinline__ float jax_erfinv(float x) {
  float w = -log1pf(-x * x);
  float p;
  if (w < 5.0f) {
    w -= 2.5f;
    p = 2.81022636e-08f;
    p = fmaf(p, w, 3.43273939e-07f);
    p = fmaf(p, w, -3.5233877e-06f);
    p = fmaf(p, w, -4.39150654e-06f);
    p = fmaf(p, w, 0.00021858087f);
    p = fmaf(p, w, -0.00125372503f);
    p = fmaf(p, w, -0.00417768164f);
    p = fmaf(p, w, 0.246640727f);
    p = fmaf(p, w, 1.50140941f);
  } else {
    w = sqrtf(w) - 3.0f;
    p = -0.000200214257f;
    p = fmaf(p, w, 0.000100950558f);
    p = fmaf(p, w, 0.00134934322f);
    p = fmaf(p, w, -0.00367342844f);
    p = fmaf(p, w, 0.00573950773f);
    p = fmaf(p, w, -0.0076224613f);
    p = fmaf(p, w, 0.00943887047f);
    p = fmaf(p, w, 1.00167406f);
    p = fmaf(p, w, 2.83297682f);
  }
  return p * x;
}

__device__ __forceinline__ float uni_from_bits(uint32_t bits) {
  float f = __uint_as_float((bits >> 9) | 0x3f800000u) - 1.0f;
  float x = f * 2.0f + (-0.99999994f);
  return fmaxf(-0.99999994f, x);
}

__device__ __forceinline__ float noise_from_bits(uint32_t bits) {
  float n = 1.41421356f * jax_erfinv(uni_from_bits(bits));
  return 0.15811388f * n;   // sqrt(2/A)*SIG = sqrt(10)*0.05
}

__device__ __forceinline__ float my_tanh(float x) {
  float e = __expf(2.0f * x);
  return 1.0f - 2.0f / (e + 1.0f);
}

// ---------------------------------------------------------------------------
__global__ __launch_bounds__(256) void build_w_kernel(
    const float* __restrict__ w_ll, const float* __restrict__ w_rl,
    const float* __restrict__ w_lr, const float* __restrict__ w_rr,
    float* __restrict__ Wmain, float* __restrict__ Wtail) {
  int i = blockIdx.x * 256 + threadIdx.x;
  if (i >= 258 * 258) return;
  int j = i / 258, k = i - j * 258;
  float val;
  if (j < 2) val = (k < 2) ? w_ll[j * 2 + k] : w_rl[j * 256 + (k - 2)];
  else       val = (k < 2) ? w_lr[(j - 2) * 2 + k] : w_rr[(j - 2) * 256 + (k - 2)];
  if (k < 256) Wmain[j * 256 + k] = val;
  else         Wtail[j * 2 + (k - 256)] = val;
}

// ---------------------------------------------------------------------------
__global__ __launch_bounds__(256) void gen_uv_kernel(
    const float* __restrict__ xs, float* __restrict__ u, float* __restrict__ v,
    uint32_t k0a, uint32_t k0b, uint32_t k1a, uint32_t k1b) {
  uint32_t i = blockIdx.x * 256u + threadIdx.x;
  bool isv = i >= 409600u;
  uint32_t e = isv ? i - 409600u : i;
  uint32_t ka = isv ? k1a : k0a;
  uint32_t kb = isv ? k1b : k0b;
  uint32_t o0, o1;
  tf2x32(ka, kb, 0u, e, o0, o1);
  float val = xs[e] + noise_from_bits(o0 ^ o1);
  if (isv) v[e] = val; else u[e] = val;
}

// ---------------------------------------------------------------------------
__global__ __launch_bounds__(256) void gen_c_kernel(
    const float* __restrict__ u, const float* __restrict__ v,
    const float* __restrict__ w_xl, const float* __restrict__ w_xr,
    const float* __restrict__ b_ll, const float* __restrict__ b_rr,
    float* __restrict__ C, uint32_t ka, uint32_t kb) {
  uint32_t i = blockIdx.x * 256u + threadIdx.x;   // < 52,838,400
  uint32_t t = i / 132096u;
  uint32_t rem = i - t * 132096u;
  uint32_t b = rem / 258u;
  uint32_t j = rem - b * 258u;
  uint32_t o0, o1;
  tf2x32(ka, kb, 0u, i, o0, o1);
  float nz = noise_from_bits(o0 ^ o1);
  uint32_t bt = (b * 400u + t) * 2u;
  float inj;
  if (j < 2u) {
    float2 uu = *(const float2*)(u + bt);
    inj = w_xl[j * 2u] * uu.x + w_xl[j * 2u + 1u] * uu.y + b_ll[j];
  } else {
    uint32_t jr = j - 2u;
    float2 vv = *(const float2*)(v + bt);
    inj = w_xr[jr * 2u] * vv.x + w_xr[jr * 2u + 1u] * vv.y + b_rr[jr];
  }
  C[(size_t)(b * 400u + t) * 258u + j] = inj + nz;
}

// ---------------------------------------------------------------------------
// K_scan: 256 blocks x 1024 threads; block = batch rows b0, b0+1.
// Matvec as in R2 (per-thread W rows joutA/joutB, 8-way ks split, skewed h).
// NEW: C staged through LDS (cbuf double buffer, 1-step register prefetch),
// hs stored by cooperative coalesced copy of hbuf. Zero scattered global ops.
// ---------------------------------------------------------------------------
#define HROW 292

__device__ __forceinline__ void dot4(float& acc, const float* W, int o, float4 q) {
  acc = fmaf(W[o], q.x, acc);
  acc = fmaf(W[o + 1], q.y, acc);
  acc = fmaf(W[o + 2], q.z, acc);
  acc = fmaf(W[o + 3], q.w, acc);
}

__global__ __launch_bounds__(1024) void rnn_scan_kernel(
    const float* __restrict__ Wmain, const float* __restrict__ Wtail,
    float* __restrict__ hsC) {
  __shared__ __align__(16) float hbuf[4 * HROW];
  __shared__ __align__(16) float cbuf[2][516];
  __shared__ __align__(16) float wlds[512];

  const int tid = threadIdx.x;
  const int b0 = blockIdx.x * 2;
  const int ks = tid & 7;
  const int g = tid >> 3;
  const int joutA = g + 2;
  const int joutB = g + 130;

  // --- persistent W registers ---
  float wA[32], wB[32];
  {
    const float* pA = Wmain + joutA * 256 + ks * 32;
    const float* pB = Wmain + joutB * 256 + ks * 32;
#pragma unroll
    for (int c = 0; c < 8; ++c) {
      float4 a = *(const float4*)(pA + 4 * c);
      float4 bq = *(const float4*)(pB + 4 * c);
      wA[4 * c] = a.x; wA[4 * c + 1] = a.y; wA[4 * c + 2] = a.z; wA[4 * c + 3] = a.w;
      wB[4 * c] = bq.x; wB[4 * c + 1] = bq.y; wB[4 * c + 2] = bq.z; wB[4 * c + 3] = bq.w;
    }
  }
  const float wtA0 = Wtail[joutA * 2], wtA1 = Wtail[joutA * 2 + 1];
  const float wtB0 = Wtail[joutB * 2], wtB1 = Wtail[joutB * 2 + 1];

  const bool lupd = (tid == 32) || (tid == 33);
  float wtL0 = 0.f, wtL1 = 0.f, hL0 = 0.f, hL1 = 0.f;
  if (lupd) { int jo = tid & 1; wtL0 = Wtail[jo * 2]; wtL1 = Wtail[jo * 2 + 1]; }

  float hA = 0.f, hB = 0.f;

  // --- cooperative C-load / hs-store lane mapping (tid < 516) ---
  const bool cact = (tid < 516);
  const int cr = (tid >= 258) ? 1 : 0;
  const int cj = cact ? (tid - 258 * cr) : 0;
  const int cslot = (cj < 256) ? (36 * (cj >> 5) + (cj & 31)) : (288 + cj - 256);
  float* gC = hsC + (size_t)(b0 + cr) * 103200 + cj;   // + t*258

  if (tid < 512) wlds[tid] = Wmain[tid];               // W rows 0,1
  for (int k2 = tid; k2 < 4 * HROW; k2 += 1024) hbuf[k2] = 0.f;
  if (cact) cbuf[0][tid] = gC[0];                      // C(t=0)
  __syncthreads();

  const int dA = 36 * (joutA >> 5) + (joutA & 31);
  const int dB = 36 * (joutB >> 5) + (joutB & 31);

#pragma unroll 1
  for (int t = 0; t < 400; ++t) {
    const int cur = t & 1;
    const float* h0 = hbuf + cur * 2 * HROW;
    const float* h1 = h0 + HROW;

    // (1) prefetch C(t+1) into registers — latency hides under the matvec
    float creg = 0.f;
    if (cact && t < 399) creg = gC[(t + 1) * 258];

    // (2) coalesced store of hs[:, t-1]  (= h(t), stable in hbuf[cur])
    if (cact && t > 0) gC[(t - 1) * 258] = h0[cr * HROW + cslot];

    // (3) matvec partial dots, k in [32ks, 32ks+32)
    float aA0 = 0.f, aA1 = 0.f, aB0 = 0.f, aB1 = 0.f;
    const float* hp0 = h0 + 36 * ks;
    const float* hp1 = h1 + 36 * ks;
#pragma unroll
    for (int c = 0; c < 8; ++c) {
      float4 x0 = *(const float4*)(hp0 + 4 * c);
      float4 x1 = *(const float4*)(hp1 + 4 * c);
      dot4(aA0, wA, 4 * c, x0);
      dot4(aA1, wA, 4 * c, x1);
      dot4(aB0, wB, 4 * c, x0);
      dot4(aB1, wB, 4 * c, x1);
    }

    // (4) left outputs (j=0,1), wave 0
    float l00 = 0.f, l01 = 0.f, l10 = 0.f, l11 = 0.f;
    if (tid < 64) {
      const int dwo = 36 * (tid >> 3) + ((4 * tid) & 31);
      float4 x0 = *(const float4*)(h0 + dwo);
      float4 x1 = *(const float4*)(h1 + dwo);
      float4 w0v = *(const float4*)(wlds + 4 * tid);
      float4 w1v = *(const float4*)(wlds + 256 + 4 * tid);
      l00 = w0v.x * x0.x + w0v.y * x0.y + w0v.z * x0.z + w0v.w * x0.w;
      l01 = w1v.x * x0.x + w1v.y * x0.y + w1v.z * x0.z + w1v.w * x0.w;
      l10 = w0v.x * x1.x + w0v.y * x1.y + w0v.z * x1.z + w0v.w * x1.w;
      l11 = w1v.x * x1.x + w1v.y * x1.y + w1v.z * x1.z + w1v.w * x1.w;
#pragma unroll
      for (int m = 1; m < 64; m <<= 1) {
        l00 += __shfl_xor(l00, m);
        l01 += __shfl_xor(l01, m);
        l10 += __shfl_xor(l10, m);
        l11 += __shfl_xor(l11, m);
      }
    }

    // (5) 8-lane butterfly over ks
#pragma unroll
    for (int m = 1; m < 8; m <<= 1) {
      aA0 += __shfl_xor(aA0, m);
      aA1 += __shfl_xor(aA1, m);
      aB0 += __shfl_xor(aB0, m);
      aB1 += __shfl_xor(aB1, m);
    }

    float* hn = hbuf + (cur ^ 1) * 2 * HROW;

    // (6) update: lane ks=r owns batch-row r for joutA/joutB; C from LDS
    if (ks < 2) {
      const float* hr = ks ? h1 : h0;
      float accA = ks ? aA1 : aA0;
      float accB = ks ? aB1 : aB0;
      float cA = cbuf[cur][ks * 258 + joutA];
      float cB = cbuf[cur][ks * 258 + joutB];
      float t256 = hr[288], t257 = hr[289];
      float preA = accA + wtA0 * t256 + wtA1 * t257 + cA;
      float preB = accB + wtB0 * t256 + wtB1 * t257 + cB;
      hA = 0.8f * hA + 0.2f * my_tanh(preA);
      hB = 0.8f * hB + 0.2f * my_tanh(preB);
      float* hnr = hn + ks * HROW;
      hnr[dA] = hA;
      hnr[dB] = hB;
    }
    if (lupd) {
      int jo = tid & 1;
      float a0 = jo ? l01 : l00;
      float a1 = jo ? l11 : l10;
      float cL0 = cbuf[cur][jo];
      float cL1 = cbuf[cur][258 + jo];
      float pre0 = a0 + wtL0 * h0[288] + wtL1 * h0[289] + cL0;
      float pre1 = a1 + wtL0 * h1[288] + wtL1 * h1[289] + cL1;
      hL0 = 0.8f * hL0 + 0.2f * my_tanh(pre0);
      hL1 = 0.8f * hL1 + 0.2f * my_tanh(pre1);
      hn[jo] = hL0;
      hn[HROW + jo] = hL1;
    }

    // (7) commit prefetched C(t+1) to the next LDS buffer
    if (cact && t < 399) cbuf[cur ^ 1][tid] = creg;

    // (8) single barrier per step
    __syncthreads();
  }

  // epilogue: hs[:, 399] from hbuf[cur(400)=0]
  if (cact) gC[399 * 258] = hbuf[cr * HROW + cslot];
}

// ---------------------------------------------------------------------------
__global__ __launch_bounds__(256) void zs_kernel(
    const float* __restrict__ hs, const float* __restrict__ w_ro,
    const float* __restrict__ b_ro, float* __restrict__ zs) {
  int gtid = blockIdx.x * 256 + threadIdx.x;
  int row = gtid >> 6;
  int lane = threadIdx.x & 63;
  const float* hrow = hs + (size_t)row * 258;
  float s = 0.f;
  for (int j = lane; j < 258; j += 64) s = fmaf(hrow[j], w_ro[j], s);
#pragma unroll
  for (int m = 32; m >= 1; m >>= 1) s += __shfl_xor(s, m);
  if (lane == 0) zs[row] = s + b_ro[0];
}

// ---------------------------------------------------------------------------
extern "C" void kernel_launch(void* const* d_in, const int* in_sizes, int n_in,
                              void* d_out, int out_size, void* d_ws, size_t ws_size,
                              hipStream_t stream) {
  const float* xs   = (const float*)d_in[0];
  const float* w_ll = (const float*)d_in[1];
  const float* b_ll = (const float*)d_in[2];
  const float* w_rr = (const float*)d_in[3];
  const float* b_rr = (const float*)d_in[4];
  const float* w_lr = (const float*)d_in[5];
  const float* w_rl = (const float*)d_in[6];
  const float* w_xl = (const float*)d_in[7];
  const float* w_xr = (const float*)d_in[8];
  const float* w_ro = (const float*)d_in[9];
  const float* b_ro = (const float*)d_in[10];

  float* hs = (float*)d_out;                    // 512*400*258
  float* zs = hs + (size_t)52838400;

  float* Wmain = (float*)d_ws;                  // 66,048
  float* Wtail = Wmain + 66048;                 // 516
  float* u     = Wtail + 516;                   // 409,600
  float* v     = u + 409600;                    // 409,600

  uint32_t nk[3][2];
  for (uint32_t i = 0; i < 3; ++i) {
    uint32_t o0, o1;
    tf2x32(0u, 42u, 0u, i, o0, o1);
    nk[i][0] = o0; nk[i][1] = o1;
  }

  build_w_kernel<<<(258 * 258 + 255) / 256, 256, 0, stream>>>(w_ll, w_rl, w_lr, w_rr, Wmain, Wtail);
  gen_uv_kernel<<<3200, 256, 0, stream>>>(xs, u, v, nk[0][0], nk[0][1], nk[1][0], nk[1][1]);
  gen_c_kernel<<<206400, 256, 0, stream>>>(u, v, w_xl, w_xr, b_ll, b_rr, hs, nk[2][0], nk[2][1]);
  rnn_scan_kernel<<<256, 1024, 0, stream>>>(Wmain, Wtail, hs);
  zs_kernel<<<51200, 256, 0, stream>>>(hs, w_ro, b_ro, zs);
}

// Round 4
// 1840.262 us; speedup vs baseline: 2.1822x; 1.8645x over previous
//
#include <hip/hip_runtime.h>
#include <stdint.h>
#include <stddef.h>

// ---------------------------------------------------------------------------
// TwoHemiRNNTanh_asymmetric_single_readout  (B=512, T=400, hidden 258)
// R4: scan restructure. 256 blocks x 512 thr (8 waves). Thread (g,ks) owns
// 4 W-rows x 32-k chunk x 2 batch rows, W fully register-resident (128 VGPR).
// DPP allreduce (xor1/xor2 on VALU) + 1 ds_swizzle (xor4). C/hs staged in
// 8-step LDS chunks with register prefetch -> no per-step global traffic.
// ---------------------------------------------------------------------------

#define TF_ROUND(x0, x1, r) { x0 += x1; x1 = ((x1) << (r)) | ((x1) >> (32 - (r))); x1 ^= x0; }

__host__ __device__ inline void tf2x32(uint32_t k0, uint32_t k1, uint32_t x0, uint32_t x1,
                                       uint32_t& o0, uint32_t& o1) {
  uint32_t ks2 = k0 ^ k1 ^ 0x1BD11BDAu;
  x0 += k0; x1 += k1;
  TF_ROUND(x0, x1, 13) TF_ROUND(x0, x1, 15) TF_ROUND(x0, x1, 26) TF_ROUND(x0, x1, 6)
  x0 += k1; x1 += ks2 + 1u;
  TF_ROUND(x0, x1, 17) TF_ROUND(x0, x1, 29) TF_ROUND(x0, x1, 16) TF_ROUND(x0, x1, 24)
  x0 += ks2; x1 += k0 + 2u;
  TF_ROUND(x0, x1, 13) TF_ROUND(x0, x1, 15) TF_ROUND(x0, x1, 26) TF_ROUND(x0, x1, 6)
  x0 += k0; x1 += k1 + 3u;
  TF_ROUND(x0, x1, 17) TF_ROUND(x0, x1, 29) TF_ROUND(x0, x1, 16) TF_ROUND(x0, x1, 24)
  x0 += k1; x1 += ks2 + 4u;
  TF_ROUND(x0, x1, 13) TF_ROUND(x0, x1, 15) TF_ROUND(x0, x1, 26) TF_ROUND(x0, x1, 6)
  x0 += ks2; x1 += k0 + 5u;
  o0 = x0; o1 = x1;
}

__device__ __forceinline__ float jax_erfinv(float x) {
  float w = -log1pf(-x * x);
  float p;
  if (w < 5.0f) {
    w -= 2.5f;
    p = 2.81022636e-08f;
    p = fmaf(p, w, 3.43273939e-07f);
    p = fmaf(p, w, -3.5233877e-06f);
    p = fmaf(p, w, -4.39150654e-06f);
    p = fmaf(p, w, 0.00021858087f);
    p = fmaf(p, w, -0.00125372503f);
    p = fmaf(p, w, -0.00417768164f);
    p = fmaf(p, w, 0.246640727f);
    p = fmaf(p, w, 1.50140941f);
  } else {
    w = sqrtf(w) - 3.0f;
    p = -0.000200214257f;
    p = fmaf(p, w, 0.000100950558f);
    p = fmaf(p, w, 0.00134934322f);
    p = fmaf(p, w, -0.00367342844f);
    p = fmaf(p, w, 0.00573950773f);
    p = fmaf(p, w, -0.0076224613f);
    p = fmaf(p, w, 0.00943887047f);
    p = fmaf(p, w, 1.00167406f);
    p = fmaf(p, w, 2.83297682f);
  }
  return p * x;
}

__device__ __forceinline__ float uni_from_bits(uint32_t bits) {
  float f = __uint_as_float((bits >> 9) | 0x3f800000u) - 1.0f;
  float x = f * 2.0f + (-0.99999994f);
  return fmaxf(-0.99999994f, x);
}

__device__ __forceinline__ float noise_from_bits(uint32_t bits) {
  float n = 1.41421356f * jax_erfinv(uni_from_bits(bits));
  return 0.15811388f * n;   // sqrt(2/A)*SIG = sqrt(10)*0.05
}

__device__ __forceinline__ float my_tanh(float x) {
  float e = __expf(2.0f * x);
  return 1.0f - 2.0f / (e + 1.0f);
}

// 8-lane (octet) allreduce: xor1,xor2 on VALU via DPP quad_perm; xor4 via swizzle
__device__ __forceinline__ float allred8(float x) {
  int t = __builtin_amdgcn_update_dpp(0, __float_as_int(x), 0xB1, 0xF, 0xF, true);
  x += __int_as_float(t);
  t = __builtin_amdgcn_update_dpp(0, __float_as_int(x), 0x4E, 0xF, 0xF, true);
  x += __int_as_float(t);
  t = __builtin_amdgcn_ds_swizzle(__float_as_int(x), 0x101F);
  x += __int_as_float(t);
  return x;
}

// ---------------------------------------------------------------------------
__global__ __launch_bounds__(256) void build_w_kernel(
    const float* __restrict__ w_ll, const float* __restrict__ w_rl,
    const float* __restrict__ w_lr, const float* __restrict__ w_rr,
    float* __restrict__ Wmain, float* __restrict__ Wtail) {
  int i = blockIdx.x * 256 + threadIdx.x;
  if (i >= 258 * 258) return;
  int j = i / 258, k = i - j * 258;
  float val;
  if (j < 2) val = (k < 2) ? w_ll[j * 2 + k] : w_rl[j * 256 + (k - 2)];
  else       val = (k < 2) ? w_lr[(j - 2) * 2 + k] : w_rr[(j - 2) * 256 + (k - 2)];
  if (k < 256) Wmain[j * 256 + k] = val;
  else         Wtail[j * 2 + (k - 256)] = val;
}

// ---------------------------------------------------------------------------
__global__ __launch_bounds__(256) void gen_uv_kernel(
    const float* __restrict__ xs, float* __restrict__ u, float* __restrict__ v,
    uint32_t k0a, uint32_t k0b, uint32_t k1a, uint32_t k1b) {
  uint32_t i = blockIdx.x * 256u + threadIdx.x;
  bool isv = i >= 409600u;
  uint32_t e = isv ? i - 409600u : i;
  uint32_t ka = isv ? k1a : k0a;
  uint32_t kb = isv ? k1b : k0b;
  uint32_t o0, o1;
  tf2x32(ka, kb, 0u, e, o0, o1);
  float val = xs[e] + noise_from_bits(o0 ^ o1);
  if (isv) v[e] = val; else u[e] = val;
}

// ---------------------------------------------------------------------------
__global__ __launch_bounds__(256) void gen_c_kernel(
    const float* __restrict__ u, const float* __restrict__ v,
    const float* __restrict__ w_xl, const float* __restrict__ w_xr,
    const float* __restrict__ b_ll, const float* __restrict__ b_rr,
    float* __restrict__ C, uint32_t ka, uint32_t kb) {
  uint32_t i = blockIdx.x * 256u + threadIdx.x;   // < 52,838,400
  uint32_t t = i / 132096u;
  uint32_t rem = i - t * 132096u;
  uint32_t b = rem / 258u;
  uint32_t j = rem - b * 258u;
  uint32_t o0, o1;
  tf2x32(ka, kb, 0u, i, o0, o1);
  float nz = noise_from_bits(o0 ^ o1);
  uint32_t bt = (b * 400u + t) * 2u;
  float inj;
  if (j < 2u) {
    float2 uu = *(const float2*)(u + bt);
    inj = w_xl[j * 2u] * uu.x + w_xl[j * 2u + 1u] * uu.y + b_ll[j];
  } else {
    uint32_t jr = j - 2u;
    float2 vv = *(const float2*)(v + bt);
    inj = w_xr[jr * 2u] * vv.x + w_xr[jr * 2u + 1u] * vv.y + b_rr[jr];
  }
  C[(size_t)(b * 400u + t) * 258u + j] = inj + nz;
}

// ---------------------------------------------------------------------------
// K_scan. h slot layout (skewed, conflict-free): k -> 36*(k>>5) + (k&31);
// k=256,257 -> 288,289. cb/sb chunk layout: [row][s][jj], jj = j<2?256+j:j-2,
// s-stride 260 (keeps 4g f4 reads aligned).
// ---------------------------------------------------------------------------
__global__ __launch_bounds__(512, 2) void rnn_scan_kernel(
    const float* __restrict__ Wmain, const float* __restrict__ Wtail,
    float* __restrict__ hsC) {
  __shared__ __align__(16) float cb[2][8][260];   // C chunk
  __shared__ __align__(16) float sb[2][8][260];   // hs chunk out
  __shared__ __align__(16) float hb[2][2][292];   // h double buffer
  __shared__ __align__(16) float wl[2][292];      // W rows 0,1 (skewed)

  const int tid = threadIdx.x;
  const int b0 = blockIdx.x * 2;
  const int ks = tid & 7;
  const int g  = tid >> 3;
  const int j0 = 2 + 4 * g;

  // persistent W registers: 4 rows x 32 k
  float4 wv[4][8];
  float2 wt[4];
#pragma unroll
  for (int r = 0; r < 4; ++r) {
    const float* p = Wmain + (j0 + r) * 256 + 32 * ks;
#pragma unroll
    for (int c = 0; c < 8; ++c) wv[r][c] = *(const float4*)(p + 4 * c);
    wt[r] = *(const float2*)(Wtail + (j0 + r) * 2);
  }

  for (int idx = tid; idx < 516; idx += 512) {
    int row = idx >= 258; int k = idx - 258 * row;
    int sl = (k < 256) ? (36 * (k >> 5) + (k & 31)) : (288 + (k - 256));
    wl[row][sl] = (k < 256) ? Wmain[row * 256 + k] : Wtail[row * 2 + (k - 256)];
  }
  for (int idx = tid; idx < 2 * 2 * 292; idx += 512) ((float*)hb)[idx] = 0.f;

  const float* gr0 = hsC + (size_t)b0 * 103200;
  const float* gr1 = gr0 + 103200;
  float* ow0 = hsC + (size_t)b0 * 103200;
  float* ow1 = ow0 + 103200;

  // prologue: chunk 0 -> cb
  for (int idx = tid; idx < 4128; idx += 512) {
    int ro = idx >= 2064; int ii = idx - 2064 * ro;
    int s = ii / 258; int j = ii - 258 * s;
    int jj = (j < 2) ? (256 + j) : (j - 2);
    cb[ro][s][jj] = ro ? gr1[ii] : gr0[ii];
  }
  __syncthreads();

  float hcur[4] = {0.f, 0.f, 0.f, 0.f};   // updater lanes (ks<2): own 4 rows
  float hL0 = 0.f, hL1 = 0.f;             // lanes 0,1: left rows j=0,1

#pragma unroll 1
  for (int cc = 0; cc < 50; ++cc) {
    // prefetch next C chunk into registers (in flight during the 8 steps)
    float creg[9];
    const bool hn = (cc < 49);
    const int nb = (cc + 1) * 2064;
    if (hn) {
#pragma unroll
      for (int q = 0; q < 9; ++q) {
        int idx = tid + 512 * q;
        if (idx < 4128) {
          int ro = idx >= 2064; int ii = idx - 2064 * ro;
          creg[q] = ro ? gr1[nb + ii] : gr0[nb + ii];
        }
      }
    }

#pragma unroll
    for (int s = 0; s < 8; ++s) {
      const int cur = s & 1, nxt = cur ^ 1;

      // main dot: 4 rows x 2 batch, k chunk [32ks, 32ks+32)
      float a0[4] = {0.f, 0.f, 0.f, 0.f}, a1[4] = {0.f, 0.f, 0.f, 0.f};
#pragma unroll
      for (int c = 0; c < 8; ++c) {
        float4 x0 = *(const float4*)&hb[cur][0][36 * ks + 4 * c];
        float4 x1 = *(const float4*)&hb[cur][1][36 * ks + 4 * c];
#pragma unroll
        for (int r = 0; r < 4; ++r) {
          float4 w = wv[r][c];
          a0[r] = fmaf(w.x, x0.x, a0[r]); a0[r] = fmaf(w.y, x0.y, a0[r]);
          a0[r] = fmaf(w.z, x0.z, a0[r]); a0[r] = fmaf(w.w, x0.w, a0[r]);
          a1[r] = fmaf(w.x, x1.x, a1[r]); a1[r] = fmaf(w.y, x1.y, a1[r]);
          a1[r] = fmaf(w.z, x1.z, a1[r]); a1[r] = fmaf(w.w, x1.w, a1[r]);
        }
      }

      // left rows (j=0,1) partials: lanes 0..7 only (wave 0)
      float l00 = 0.f, l01 = 0.f, l10 = 0.f, l11 = 0.f;
      if (tid < 8) {
#pragma unroll
        for (int c = 0; c < 8; ++c) {
          float4 x0 = *(const float4*)&hb[cur][0][36 * ks + 4 * c];
          float4 x1 = *(const float4*)&hb[cur][1][36 * ks + 4 * c];
          float4 w0 = *(const float4*)&wl[0][36 * ks + 4 * c];
          float4 w1 = *(const float4*)&wl[1][36 * ks + 4 * c];
          l00 += w0.x * x0.x + w0.y * x0.y + w0.z * x0.z + w0.w * x0.w;
          l01 += w1.x * x0.x + w1.y * x0.y + w1.z * x0.z + w1.w * x0.w;
          l10 += w0.x * x1.x + w0.y * x1.y + w0.z * x1.z + w0.w * x1.w;
          l11 += w1.x * x1.x + w1.y * x1.y + w1.z * x1.z + w1.w * x1.w;
        }
        l00 = allred8(l00); l01 = allred8(l01);
        l10 = allred8(l10); l11 = allred8(l11);
      }

      // allreduce over the 8 ks lanes (2 DPP adds + 1 swizzle each)
#pragma unroll
      for (int r = 0; r < 4; ++r) { a0[r] = allred8(a0[r]); a1[r] = allred8(a1[r]); }

      // update right rows: lane ks=0 -> batch row 0, ks=1 -> batch row 1
      if (ks < 2) {
        const float* hr = hb[cur][ks];
        float t0 = hr[288], t1 = hr[289];
        float4 cv = *(const float4*)&cb[ks][s][4 * g];
        float cvr[4] = {cv.x, cv.y, cv.z, cv.w};
#pragma unroll
        for (int r = 0; r < 4; ++r) {
          float acc = ks ? a1[r] : a0[r];
          float pre = acc + wt[r].x * t0 + wt[r].y * t1 + cvr[r];
          hcur[r] = 0.8f * hcur[r] + 0.2f * my_tanh(pre);
        }
#pragma unroll
        for (int r = 0; r < 4; ++r) {
          int j = j0 + r;
          hb[nxt][ks][36 * (j >> 5) + (j & 31)] = hcur[r];
        }
        *(float4*)&sb[ks][s][4 * g] = make_float4(hcur[0], hcur[1], hcur[2], hcur[3]);
      }

      // left updaters: lane 0 = batch 0, lane 1 = batch 1
      if (tid < 2) {
        const float* hr = hb[cur][tid];
        float t0 = hr[288], t1 = hr[289];
        float la = tid ? l10 : l00;
        float lb = tid ? l11 : l01;
        float pre0 = la + wl[0][288] * t0 + wl[0][289] * t1 + cb[tid][s][256];
        float pre1 = lb + wl[1][288] * t0 + wl[1][289] * t1 + cb[tid][s][257];
        hL0 = 0.8f * hL0 + 0.2f * my_tanh(pre0);
        hL1 = 0.8f * hL1 + 0.2f * my_tanh(pre1);
        hb[nxt][tid][0] = hL0;
        hb[nxt][tid][1] = hL1;
        sb[tid][s][256] = hL0;
        sb[tid][s][257] = hL1;
      }

      __syncthreads();
    }

    // flush sb -> hs (coalesced), then commit prefetched C chunk -> cb
    const int fb = cc * 2064;
    for (int idx = tid; idx < 4128; idx += 512) {
      int ro = idx >= 2064; int ii = idx - 2064 * ro;
      int s = ii / 258; int j = ii - 258 * s;
      int jj = (j < 2) ? (256 + j) : (j - 2);
      float vv = sb[ro][s][jj];
      if (ro) ow1[fb + ii] = vv; else ow0[fb + ii] = vv;
    }
    if (hn) {
#pragma unroll
      for (int q = 0; q < 9; ++q) {
        int idx = tid + 512 * q;
        if (idx < 4128) {
          int ro = idx >= 2064; int ii = idx - 2064 * ro;
          int s = ii / 258; int j = ii - 258 * s;
          int jj = (j < 2) ? (256 + j) : (j - 2);
          cb[ro][s][jj] = creg[q];
        }
      }
    }
    __syncthreads();
  }
}

// ---------------------------------------------------------------------------
__global__ __launch_bounds__(256) void zs_kernel(
    const float* __restrict__ hs, const float* __restrict__ w_ro,
    const float* __restrict__ b_ro, float* __restrict__ zs) {
  int gtid = blockIdx.x * 256 + threadIdx.x;
  int row = gtid >> 6;
  int lane = threadIdx.x & 63;
  const float* hrow = hs + (size_t)row * 258;
  float s = 0.f;
  for (int j = lane; j < 258; j += 64) s = fmaf(hrow[j], w_ro[j], s);
#pragma unroll
  for (int m = 32; m >= 1; m >>= 1) s += __shfl_xor(s, m);
  if (lane == 0) zs[row] = s + b_ro[0];
}

// ---------------------------------------------------------------------------
extern "C" void kernel_launch(void* const* d_in, const int* in_sizes, int n_in,
                              void* d_out, int out_size, void* d_ws, size_t ws_size,
                              hipStream_t stream) {
  const float* xs   = (const float*)d_in[0];
  const float* w_ll = (const float*)d_in[1];
  const float* b_ll = (const float*)d_in[2];
  const float* w_rr = (const float*)d_in[3];
  const float* b_rr = (const float*)d_in[4];
  const float* w_lr = (const float*)d_in[5];
  const float* w_rl = (const float*)d_in[6];
  const float* w_xl = (const float*)d_in[7];
  const float* w_xr = (const float*)d_in[8];
  const float* w_ro = (const float*)d_in[9];
  const float* b_ro = (const float*)d_in[10];

  float* hs = (float*)d_out;                    // 512*400*258
  float* zs = hs + (size_t)52838400;

  float* Wmain = (float*)d_ws;                  // 66,048
  float* Wtail = Wmain + 66048;                 // 516
  float* u     = Wtail + 516;                   // 409,600
  float* v     = u + 409600;                    // 409,600

  uint32_t nk[3][2];
  for (uint32_t i = 0; i < 3; ++i) {
    uint32_t o0, o1;
    tf2x32(0u, 42u, 0u, i, o0, o1);
    nk[i][0] = o0; nk[i][1] = o1;
  }

  build_w_kernel<<<(258 * 258 + 255) / 256, 256, 0, stream>>>(w_ll, w_rl, w_lr, w_rr, Wmain, Wtail);
  gen_uv_kernel<<<3200, 256, 0, stream>>>(xs, u, v, nk[0][0], nk[0][1], nk[1][0], nk[1][1]);
  gen_c_kernel<<<206400, 256, 0, stream>>>(u, v, w_xl, w_xr, b_ll, b_rr, hs, nk[2][0], nk[2][1]);
  rnn_scan_kernel<<<256, 512, 0, stream>>>(Wmain, Wtail, hs);
  zs_kernel<<<51200, 256, 0, stream>>>(hs, w_ro, b_ro, zs);
}

// Round 5
// 1162.196 us; speedup vs baseline: 3.4554x; 1.5834x over previous
//
#include <hip/hip_runtime.h>
#include <stdint.h>
#include <stddef.h>

// ---------------------------------------------------------------------------
// TwoHemiRNNTanh_asymmetric_single_readout  (B=512, T=400, hidden 258)
// R5: f16-packed W (v_dot2_f32_f16) -> 64 VGPR W, 512 blocks x 1 batch row,
// 2 blocks/CU overlap. h packed f16 in LDS (stride-20 skew, conflict-free),
// h state f32. C/hs staged in 8-step LDS chunks as in R4.
// ---------------------------------------------------------------------------

typedef uint32_t u32x4 __attribute__((ext_vector_type(4)));
typedef __fp16   f16x2 __attribute__((ext_vector_type(2)));

#define TF_ROUND(x0, x1, r) { x0 += x1; x1 = ((x1) << (r)) | ((x1) >> (32 - (r))); x1 ^= x0; }

__host__ __device__ inline void tf2x32(uint32_t k0, uint32_t k1, uint32_t x0, uint32_t x1,
                                       uint32_t& o0, uint32_t& o1) {
  uint32_t ks2 = k0 ^ k1 ^ 0x1BD11BDAu;
  x0 += k0; x1 += k1;
  TF_ROUND(x0, x1, 13) TF_ROUND(x0, x1, 15) TF_ROUND(x0, x1, 26) TF_ROUND(x0, x1, 6)
  x0 += k1; x1 += ks2 + 1u;
  TF_ROUND(x0, x1, 17) TF_ROUND(x0, x1, 29) TF_ROUND(x0, x1, 16) TF_ROUND(x0, x1, 24)
  x0 += ks2; x1 += k0 + 2u;
  TF_ROUND(x0, x1, 13) TF_ROUND(x0, x1, 15) TF_ROUND(x0, x1, 26) TF_ROUND(x0, x1, 6)
  x0 += k0; x1 += k1 + 3u;
  TF_ROUND(x0, x1, 17) TF_ROUND(x0, x1, 29) TF_ROUND(x0, x1, 16) TF_ROUND(x0, x1, 24)
  x0 += k1; x1 += ks2 + 4u;
  TF_ROUND(x0, x1, 13) TF_ROUND(x0, x1, 15) TF_ROUND(x0, x1, 26) TF_ROUND(x0, x1, 6)
  x0 += ks2; x1 += k0 + 5u;
  o0 = x0; o1 = x1;
}

__device__ __forceinline__ float jax_erfinv(float x) {
  float w = -log1pf(-x * x);
  float p;
  if (w < 5.0f) {
    w -= 2.5f;
    p = 2.81022636e-08f;
    p = fmaf(p, w, 3.43273939e-07f);
    p = fmaf(p, w, -3.5233877e-06f);
    p = fmaf(p, w, -4.39150654e-06f);
    p = fmaf(p, w, 0.00021858087f);
    p = fmaf(p, w, -0.00125372503f);
    p = fmaf(p, w, -0.00417768164f);
    p = fmaf(p, w, 0.246640727f);
    p = fmaf(p, w, 1.50140941f);
  } else {
    w = sqrtf(w) - 3.0f;
    p = -0.000200214257f;
    p = fmaf(p, w, 0.000100950558f);
    p = fmaf(p, w, 0.00134934322f);
    p = fmaf(p, w, -0.00367342844f);
    p = fmaf(p, w, 0.00573950773f);
    p = fmaf(p, w, -0.0076224613f);
    p = fmaf(p, w, 0.00943887047f);
    p = fmaf(p, w, 1.00167406f);
    p = fmaf(p, w, 2.83297682f);
  }
  return p * x;
}

__device__ __forceinline__ float uni_from_bits(uint32_t bits) {
  float f = __uint_as_float((bits >> 9) | 0x3f800000u) - 1.0f;
  float x = f * 2.0f + (-0.99999994f);
  return fmaxf(-0.99999994f, x);
}

__device__ __forceinline__ float noise_from_bits(uint32_t bits) {
  float n = 1.41421356f * jax_erfinv(uni_from_bits(bits));
  return 0.15811388f * n;   // sqrt(2/A)*SIG = sqrt(10)*0.05
}

__device__ __forceinline__ float my_tanh(float x) {
  float e = __expf(2.0f * x);
  return 1.0f - 2.0f / (e + 1.0f);
}

// f16x2 dot with f32 accumulate (v_dot2_f32_f16); guarded fallback.
__device__ __forceinline__ float dot2f(uint32_t w, uint32_t h, float acc) {
#if __has_builtin(__builtin_amdgcn_fdot2)
  return __builtin_amdgcn_fdot2(__builtin_bit_cast(f16x2, w),
                                __builtin_bit_cast(f16x2, h), acc, false);
#else
  f16x2 wv = __builtin_bit_cast(f16x2, w);
  f16x2 hv = __builtin_bit_cast(f16x2, h);
  acc = fmaf((float)wv.x, (float)hv.x, acc);
  return fmaf((float)wv.y, (float)hv.y, acc);
#endif
}

__device__ __forceinline__ uint32_t packh2(float a, float b) {
  f16x2 h = __builtin_amdgcn_cvt_pkrtz(a, b);
  return __builtin_bit_cast(uint32_t, h);
}

// 8-lane allreduce: xor1,xor2 via DPP quad_perm (VALU); xor4 via ds_swizzle.
__device__ __forceinline__ float allred8(float x) {
  int t = __builtin_amdgcn_update_dpp(0, __float_as_int(x), 0xB1, 0xF, 0xF, true);
  x += __int_as_float(t);
  t = __builtin_amdgcn_update_dpp(0, __float_as_int(x), 0x4E, 0xF, 0xF, true);
  x += __int_as_float(t);
  t = __builtin_amdgcn_ds_swizzle(__float_as_int(x), 0x101F);
  x += __int_as_float(t);
  return x;
}

// packed-slot skew: kp in [0,128) -> 20*(kp>>4) + (kp&15); spans 160 dwords.
#define PK(kp) (20 * ((kp) >> 4) + ((kp) & 15))

// ---------------------------------------------------------------------------
// W fused row j, input k (h index): k<2 -> left weights, else right.
// ---------------------------------------------------------------------------
__device__ __forceinline__ float wval(int j, int k,
    const float* w_ll, const float* w_rl, const float* w_lr, const float* w_rr) {
  if (j < 2) return (k < 2) ? w_ll[j * 2 + k] : w_rl[j * 256 + (k - 2)];
  return (k < 2) ? w_lr[(j - 2) * 2 + k] : w_rr[(j - 2) * 256 + (k - 2)];
}

// Wp: packed f16 pairs [258][128]; Wtail: f32 [258][2] (k=256,257).
__global__ __launch_bounds__(256) void build_w_kernel(
    const float* __restrict__ w_ll, const float* __restrict__ w_rl,
    const float* __restrict__ w_lr, const float* __restrict__ w_rr,
    uint32_t* __restrict__ Wp, float* __restrict__ Wtail) {
  int i = blockIdx.x * 256 + threadIdx.x;
  if (i < 258 * 128) {
    int j = i >> 7, kp = i & 127;
    float v0 = wval(j, 2 * kp, w_ll, w_rl, w_lr, w_rr);
    float v1 = wval(j, 2 * kp + 1, w_ll, w_rl, w_lr, w_rr);
    Wp[i] = packh2(v0, v1);
  }
  if (i < 516) {
    int j = i >> 1, k = 256 + (i & 1);
    Wtail[i] = wval(j, k, w_ll, w_rl, w_lr, w_rr);
  }
}

// ---------------------------------------------------------------------------
__global__ __launch_bounds__(256) void gen_uv_kernel(
    const float* __restrict__ xs, float* __restrict__ u, float* __restrict__ v,
    uint32_t k0a, uint32_t k0b, uint32_t k1a, uint32_t k1b) {
  uint32_t i = blockIdx.x * 256u + threadIdx.x;
  bool isv = i >= 409600u;
  uint32_t e = isv ? i - 409600u : i;
  uint32_t ka = isv ? k1a : k0a;
  uint32_t kb = isv ? k1b : k0b;
  uint32_t o0, o1;
  tf2x32(ka, kb, 0u, e, o0, o1);
  float val = xs[e] + noise_from_bits(o0 ^ o1);
  if (isv) v[e] = val; else u[e] = val;
}

// ---------------------------------------------------------------------------
__global__ __launch_bounds__(256) void gen_c_kernel(
    const float* __restrict__ u, const float* __restrict__ v,
    const float* __restrict__ w_xl, const float* __restrict__ w_xr,
    const float* __restrict__ b_ll, const float* __restrict__ b_rr,
    float* __restrict__ C, uint32_t ka, uint32_t kb) {
  uint32_t i = blockIdx.x * 256u + threadIdx.x;   // < 52,838,400
  uint32_t t = i / 132096u;
  uint32_t rem = i - t * 132096u;
  uint32_t b = rem / 258u;
  uint32_t j = rem - b * 258u;
  uint32_t o0, o1;
  tf2x32(ka, kb, 0u, i, o0, o1);
  float nz = noise_from_bits(o0 ^ o1);
  uint32_t bt = (b * 400u + t) * 2u;
  float inj;
  if (j < 2u) {
    float2 uu = *(const float2*)(u + bt);
    inj = w_xl[j * 2u] * uu.x + w_xl[j * 2u + 1u] * uu.y + b_ll[j];
  } else {
    uint32_t jr = j - 2u;
    float2 vv = *(const float2*)(v + bt);
    inj = w_xr[jr * 2u] * vv.x + w_xr[jr * 2u + 1u] * vv.y + b_rr[jr];
  }
  C[(size_t)(b * 400u + t) * 258u + j] = inj + nz;
}

// ---------------------------------------------------------------------------
// K_scan: 512 blocks x 512 thr, 1 batch row/block, 2 blocks/CU.
// Thread (g,ks): 4 rows (j0=2+4g) x 32 k, W as 16 packed u32x4 (64 VGPR).
// hbp: h packed f16 (slots PK(kp)) + f32 h[256],h[257] at 160,161.
// cbuf/sbuf: 8-step chunks, jj remap (j<2 -> 256+j else j-2) for f4 alignment.
// ---------------------------------------------------------------------------
__global__ __launch_bounds__(512, 4) void rnn_scan_kernel(
    const uint32_t* __restrict__ Wp, const float* __restrict__ Wtail,
    float* __restrict__ hsC) {
  __shared__ __align__(16) uint32_t hbp[2][168];
  __shared__ __align__(16) uint32_t wlp[2][168];
  __shared__ __align__(16) float cbuf[8][260];
  __shared__ __align__(16) float sbuf[8][260];

  const int tid = threadIdx.x;
  const int ks = tid & 7;
  const int g  = tid >> 3;
  const int j0 = 2 + 4 * g;

  // persistent packed W: 4 rows x 16 k-pairs
  u32x4 wv[4][4];
  float2 wt[4];
#pragma unroll
  for (int r = 0; r < 4; ++r) {
    const uint32_t* p = Wp + (j0 + r) * 128 + 16 * ks;
#pragma unroll
    for (int c = 0; c < 4; ++c) wv[r][c] = *(const u32x4*)(p + 4 * c);
    wt[r] = *(const float2*)(Wtail + (j0 + r) * 2);
  }

  // stage left-row weights (rows 0,1) packed into LDS, skewed layout
  if (tid < 256) {
    int row = tid >> 7, kp = tid & 127;
    wlp[row][PK(kp)] = Wp[row * 128 + kp];
  }
  if (tid < 4) {
    int row = tid >> 1;
    wlp[row][160 + (tid & 1)] = __float_as_uint(Wtail[row * 2 + (tid & 1)]);
  }
  for (int idx = tid; idx < 336; idx += 512) ((uint32_t*)hbp)[idx] = 0u;

  const float* gC = hsC + (size_t)blockIdx.x * 103200;
  float* gO       = hsC + (size_t)blockIdx.x * 103200;

  // prologue: chunk 0 -> cbuf
  for (int idx = tid; idx < 2064; idx += 512) {
    int s = idx / 258, j = idx - 258 * s;
    int jj = (j < 2) ? (256 + j) : (j - 2);
    cbuf[s][jj] = gC[idx];
  }
  __syncthreads();

  float hcur[4] = {0.f, 0.f, 0.f, 0.f};
  float hL0 = 0.f, hL1 = 0.f;

#pragma unroll 1
  for (int cc = 0; cc < 50; ++cc) {
    float creg[5];
    const bool hn = (cc < 49);
    const int nb = (cc + 1) * 2064;
    if (hn) {
#pragma unroll
      for (int q = 0; q < 5; ++q) {
        int idx = tid + 512 * q;
        if (idx < 2064) creg[q] = gC[nb + idx];
      }
    }

#pragma unroll
    for (int s = 0; s < 8; ++s) {
      const int cur = s & 1, nxt = cur ^ 1;

      // main dot: 4 rows x 32 k as 64 dot2
      float a0 = 0.f, a1 = 0.f, a2 = 0.f, a3 = 0.f;
#pragma unroll
      for (int c = 0; c < 4; ++c) {
        u32x4 hq = *(const u32x4*)&hbp[cur][20 * ks + 4 * c];
        u32x4 w0 = wv[0][c], w1 = wv[1][c], w2 = wv[2][c], w3 = wv[3][c];
        a0 = dot2f(w0.x, hq.x, a0); a0 = dot2f(w0.y, hq.y, a0);
        a0 = dot2f(w0.z, hq.z, a0); a0 = dot2f(w0.w, hq.w, a0);
        a1 = dot2f(w1.x, hq.x, a1); a1 = dot2f(w1.y, hq.y, a1);
        a1 = dot2f(w1.z, hq.z, a1); a1 = dot2f(w1.w, hq.w, a1);
        a2 = dot2f(w2.x, hq.x, a2); a2 = dot2f(w2.y, hq.y, a2);
        a2 = dot2f(w2.z, hq.z, a2); a2 = dot2f(w2.w, hq.w, a2);
        a3 = dot2f(w3.x, hq.x, a3); a3 = dot2f(w3.y, hq.y, a3);
        a3 = dot2f(w3.z, hq.z, a3); a3 = dot2f(w3.w, hq.w, a3);
      }

      // left rows (j=0,1): lanes 0..7 (same h chunks, wlp from LDS)
      float l0 = 0.f, l1 = 0.f;
      if (tid < 8) {
#pragma unroll
        for (int c = 0; c < 4; ++c) {
          u32x4 hq = *(const u32x4*)&hbp[cur][20 * tid + 4 * c];
          u32x4 w0 = *(const u32x4*)&wlp[0][20 * tid + 4 * c];
          u32x4 w1 = *(const u32x4*)&wlp[1][20 * tid + 4 * c];
          l0 = dot2f(w0.x, hq.x, l0); l0 = dot2f(w0.y, hq.y, l0);
          l0 = dot2f(w0.z, hq.z, l0); l0 = dot2f(w0.w, hq.w, l0);
          l1 = dot2f(w1.x, hq.x, l1); l1 = dot2f(w1.y, hq.y, l1);
          l1 = dot2f(w1.z, hq.z, l1); l1 = dot2f(w1.w, hq.w, l1);
        }
        l0 = allred8(l0);
        l1 = allred8(l1);
      }

      a0 = allred8(a0); a1 = allred8(a1); a2 = allred8(a2); a3 = allred8(a3);

      const float t0 = __uint_as_float(hbp[cur][160]);
      const float t1 = __uint_as_float(hbp[cur][161]);

      // update right rows: lane ks==0 owns 4 rows
      if (ks == 0) {
        float4 cv = *(const float4*)&cbuf[s][4 * g];
        float pre0 = a0 + wt[0].x * t0 + wt[0].y * t1 + cv.x;
        float pre1 = a1 + wt[1].x * t0 + wt[1].y * t1 + cv.y;
        float pre2 = a2 + wt[2].x * t0 + wt[2].y * t1 + cv.z;
        float pre3 = a3 + wt[3].x * t0 + wt[3].y * t1 + cv.w;
        hcur[0] = 0.8f * hcur[0] + 0.2f * my_tanh(pre0);
        hcur[1] = 0.8f * hcur[1] + 0.2f * my_tanh(pre1);
        hcur[2] = 0.8f * hcur[2] + 0.2f * my_tanh(pre2);
        hcur[3] = 0.8f * hcur[3] + 0.2f * my_tanh(pre3);
        uint32_t p01 = packh2(hcur[0], hcur[1]);
        uint32_t p23 = packh2(hcur[2], hcur[3]);
        if (g == 63) {               // rows 254,255 packed; 256,257 f32 tail
          hbp[nxt][PK(127)] = p01;
          hbp[nxt][160] = __float_as_uint(hcur[2]);
          hbp[nxt][161] = __float_as_uint(hcur[3]);
        } else {
          hbp[nxt][PK(1 + 2 * g)] = p01;
          hbp[nxt][PK(2 + 2 * g)] = p23;
        }
        *(float4*)&sbuf[s][4 * g] = make_float4(hcur[0], hcur[1], hcur[2], hcur[3]);
      }

      // left updater: lane 0 owns rows 0,1 (h[0],h[1] -> pair kp=0)
      if (tid == 0) {
        float wl0t0 = __uint_as_float(wlp[0][160]);
        float wl0t1 = __uint_as_float(wlp[0][161]);
        float wl1t0 = __uint_as_float(wlp[1][160]);
        float wl1t1 = __uint_as_float(wlp[1][161]);
        float pre0 = l0 + wl0t0 * t0 + wl0t1 * t1 + cbuf[s][256];
        float pre1 = l1 + wl1t0 * t0 + wl1t1 * t1 + cbuf[s][257];
        hL0 = 0.8f * hL0 + 0.2f * my_tanh(pre0);
        hL1 = 0.8f * hL1 + 0.2f * my_tanh(pre1);
        hbp[nxt][0] = packh2(hL0, hL1);   // PK(0) == 0
        sbuf[s][256] = hL0;
        sbuf[s][257] = hL1;
      }

      __syncthreads();
    }

    // flush sbuf -> hs (coalesced), then commit prefetched C chunk -> cbuf
    const int fb = cc * 2064;
    for (int idx = tid; idx < 2064; idx += 512) {
      int s = idx / 258, j = idx - 258 * s;
      int jj = (j < 2) ? (256 + j) : (j - 2);
      gO[fb + idx] = sbuf[s][jj];
    }
    if (hn) {
#pragma unroll
      for (int q = 0; q < 5; ++q) {
        int idx = tid + 512 * q;
        if (idx < 2064) {
          int s = idx / 258, j = idx - 258 * s;
          int jj = (j < 2) ? (256 + j) : (j - 2);
          cbuf[s][jj] = creg[q];
        }
      }
    }
    __syncthreads();
  }
}

// ---------------------------------------------------------------------------
__global__ __launch_bounds__(256) void zs_kernel(
    const float* __restrict__ hs, const float* __restrict__ w_ro,
    const float* __restrict__ b_ro, float* __restrict__ zs) {
  int gtid = blockIdx.x * 256 + threadIdx.x;
  int row = gtid >> 6;
  int lane = threadIdx.x & 63;
  const float* hrow = hs + (size_t)row * 258;
  float s = 0.f;
  for (int j = lane; j < 258; j += 64) s = fmaf(hrow[j], w_ro[j], s);
#pragma unroll
  for (int m = 32; m >= 1; m >>= 1) s += __shfl_xor(s, m);
  if (lane == 0) zs[row] = s + b_ro[0];
}

// ---------------------------------------------------------------------------
extern "C" void kernel_launch(void* const* d_in, const int* in_sizes, int n_in,
                              void* d_out, int out_size, void* d_ws, size_t ws_size,
                              hipStream_t stream) {
  const float* xs   = (const float*)d_in[0];
  const float* w_ll = (const float*)d_in[1];
  const float* b_ll = (const float*)d_in[2];
  const float* w_rr = (const float*)d_in[3];
  const float* b_rr = (const float*)d_in[4];
  const float* w_lr = (const float*)d_in[5];
  const float* w_rl = (const float*)d_in[6];
  const float* w_xl = (const float*)d_in[7];
  const float* w_xr = (const float*)d_in[8];
  const float* w_ro = (const float*)d_in[9];
  const float* b_ro = (const float*)d_in[10];

  float* hs = (float*)d_out;                    // 512*400*258
  float* zs = hs + (size_t)52838400;

  uint32_t* Wp  = (uint32_t*)d_ws;              // 258*128 = 33,024 u32
  float* Wtail  = (float*)(Wp + 33024);         // 516
  float* u      = Wtail + 516;                  // 409,600
  float* v      = u + 409600;                   // 409,600

  uint32_t nk[3][2];
  for (uint32_t i = 0; i < 3; ++i) {
    uint32_t o0, o1;
    tf2x32(0u, 42u, 0u, i, o0, o1);
    nk[i][0] = o0; nk[i][1] = o1;
  }

  build_w_kernel<<<129, 256, 0, stream>>>(w_ll, w_rl, w_lr, w_rr, Wp, Wtail);
  gen_uv_kernel<<<3200, 256, 0, stream>>>(xs, u, v, nk[0][0], nk[0][1], nk[1][0], nk[1][1]);
  gen_c_kernel<<<206400, 256, 0, stream>>>(u, v, w_xl, w_xr, b_ll, b_rr, hs, nk[2][0], nk[2][1]);
  rnn_scan_kernel<<<512, 512, 0, stream>>>(Wp, Wtail, hs);
  zs_kernel<<<51200, 256, 0, stream>>>(hs, w_ro, b_ro, zs);
}